// Round 1
// baseline (663.931 us; speedup 1.0000x reference)
//
#include <hip/hip_runtime.h>

// Problem constants (from reference setup_inputs)
#define SEQ 2048
#define BATCH 64
#define DIM 1024

// Kernel 1: energies[b, s] = dot(hidden[b, :], enc[s, b, :])
// One wave (64 lanes) per (s, b) pair. enc row is 1024 contiguous floats
// (4 KiB). Lane i loads float4 at index j*64 + lane -> each instruction is a
// fully coalesced 1 KiB wave access. hidden[b,:] (256 KiB total) stays hot in
// L2/L3 across the whole grid.
__global__ __launch_bounds__(256) void energies_kernel(
    const float* __restrict__ hidden,   // [BATCH, DIM]
    const float* __restrict__ enc,      // [SEQ, BATCH, DIM]
    float* __restrict__ out)            // [BATCH, SEQ] energies (pre-softmax)
{
    const int wave = threadIdx.x >> 6;            // 0..3
    const int lane = threadIdx.x & 63;
    const int p = blockIdx.x * 4 + wave;          // flat (s,b) pair index
    const int b = p & (BATCH - 1);                // b fastest -> consecutive
    const int s = p >> 6;                         // enc rows are contiguous

    const float4* e4 = (const float4*)(enc + ((size_t)s * BATCH + b) * DIM);
    const float4* h4 = (const float4*)(hidden + (size_t)b * DIM);

    float acc = 0.f;
#pragma unroll
    for (int j = 0; j < 4; ++j) {
        float4 ev = e4[j * 64 + lane];
        float4 hv = h4[j * 64 + lane];
        acc += ev.x * hv.x + ev.y * hv.y + ev.z * hv.z + ev.w * hv.w;
    }

    // 64-lane wave reduction
#pragma unroll
    for (int off = 32; off > 0; off >>= 1)
        acc += __shfl_down(acc, off, 64);

    if (lane == 0)
        out[(size_t)b * SEQ + s] = acc;
}

// Kernel 2: in-place row softmax over SEQ for each b. One block per b.
__global__ __launch_bounds__(256) void softmax_kernel(float* __restrict__ out)
{
    const int b = blockIdx.x;
    float* row = out + (size_t)b * SEQ;
    const int t = threadIdx.x;
    const int lane = t & 63;
    const int wv = t >> 6;

    __shared__ float red_max[4];
    __shared__ float red_sum[4];

    float v[8];
    float m = -INFINITY;
#pragma unroll
    for (int j = 0; j < 8; ++j) {
        v[j] = row[t + j * 256];
        m = fmaxf(m, v[j]);
    }
    // wave max (all lanes end with the max)
#pragma unroll
    for (int off = 1; off < 64; off <<= 1)
        m = fmaxf(m, __shfl_xor(m, off, 64));
    if (lane == 0) red_max[wv] = m;
    __syncthreads();
    m = fmaxf(fmaxf(red_max[0], red_max[1]), fmaxf(red_max[2], red_max[3]));

    float sum = 0.f;
#pragma unroll
    for (int j = 0; j < 8; ++j) {
        v[j] = __expf(v[j] - m);
        sum += v[j];
    }
#pragma unroll
    for (int off = 1; off < 64; off <<= 1)
        sum += __shfl_xor(sum, off, 64);
    if (lane == 0) red_sum[wv] = sum;
    __syncthreads();
    sum = (red_sum[0] + red_sum[1]) + (red_sum[2] + red_sum[3]);

    const float inv = 1.0f / sum;
#pragma unroll
    for (int j = 0; j < 8; ++j)
        row[t + j * 256] = v[j] * inv;
}

extern "C" void kernel_launch(void* const* d_in, const int* in_sizes, int n_in,
                              void* d_out, int out_size, void* d_ws, size_t ws_size,
                              hipStream_t stream) {
    const float* hidden = (const float*)d_in[0];   // [1, 64, 1024]
    const float* enc    = (const float*)d_in[1];   // [2048, 64, 1024]
    float* out          = (float*)d_out;           // [64, 1, 2048]

    // 2048*64 pairs / 4 waves-per-block = 32768 blocks
    energies_kernel<<<(SEQ * BATCH) / 4, 256, 0, stream>>>(hidden, enc, out);
    softmax_kernel<<<BATCH, 256, 0, stream>>>(out);
}